// Round 1
// baseline (632.854 us; speedup 1.0000x reference)
//
#include <hip/hip_runtime.h>

typedef __attribute__((ext_vector_type(8))) short bf16x8;
typedef __attribute__((ext_vector_type(8))) unsigned short u16x8;
typedef __attribute__((ext_vector_type(4))) float f32x4;

#define DEVI static __device__ __forceinline__

// Problem constants
// B=2, L=2048, D=1024, H=16, Dh=64
constexpr int NROWS = 4096;   // B*L
constexpr int K3 = 3072;      // tripled K for split GEMMs

DEVI unsigned short f2bf(float x) {
  unsigned int u = __builtin_bit_cast(unsigned int, x);
  u += 0x7fffu + ((u >> 16) & 1u);   // round-to-nearest-even
  return (unsigned short)(u >> 16);
}
DEVI float bf2f(unsigned short v) {
  unsigned int u = ((unsigned int)v) << 16;
  return __builtin_bit_cast(float, u);
}

// ---------------- gate: sigmoid((mean|E| - 0.1)*10) per (b,l) key ----------------
__global__ void k_gate(const float* __restrict__ E, float* __restrict__ gate) {
  int i = blockIdx.x * 256 + threadIdx.x;           // 0..4095
  const float4* e = reinterpret_cast<const float4*>(E);
  float4 a = e[i * 2], b = e[i * 2 + 1];
  float s = fabsf(a.x) + fabsf(a.y) + fabsf(a.z) + fabsf(a.w)
          + fabsf(b.x) + fabsf(b.y) + fabsf(b.z) + fabsf(b.w);
  float en = s * 0.125f;
  gate[i] = 1.0f / (1.0f + __expf(-10.0f * (en - 0.1f)));
}

// ---------------- pack X (N x 1024 f32) -> [hi|hi|lo] (N x 3072 bf16) ----------------
__global__ void k_pack_split(const float* __restrict__ X, unsigned short* __restrict__ Xp) {
  int t = blockIdx.x * 256 + threadIdx.x;
  int idx = t << 3;
  int m = idx >> 10, k = idx & 1023;
  const float4* src = reinterpret_cast<const float4*>(X + idx);
  float4 a = src[0], b = src[1];
  float xs[8] = {a.x, a.y, a.z, a.w, b.x, b.y, b.z, b.w};
  u16x8 hi, lo;
#pragma unroll
  for (int j = 0; j < 8; ++j) {
    unsigned short h = f2bf(xs[j]);
    hi[j] = h;
    lo[j] = f2bf(xs[j] - bf2f(h));
  }
  unsigned short* base = Xp + (size_t)m * K3 + k;
  *reinterpret_cast<u16x8*>(base) = hi;
  *reinterpret_cast<u16x8*>(base + 1024) = hi;
  *reinterpret_cast<u16x8*>(base + 2048) = lo;
}

// ---------------- pack X (N x 1024 f32) -> plain bf16 (N x 1024) ----------------
__global__ void k_pack_plain(const float* __restrict__ X, unsigned short* __restrict__ Xp) {
  int t = blockIdx.x * 256 + threadIdx.x;
  int idx = t << 3;
  const float4* src = reinterpret_cast<const float4*>(X + idx);
  float4 a = src[0], b = src[1];
  float xs[8] = {a.x, a.y, a.z, a.w, b.x, b.y, b.z, b.w};
  u16x8 hi;
#pragma unroll
  for (int j = 0; j < 8; ++j) hi[j] = f2bf(xs[j]);
  *reinterpret_cast<u16x8*>(Xp + idx) = hi;
}

// ---------------- pack W (1024x1024) -> transposed split (1024 x 3072) [hi|lo|hi] ----------------
__global__ void k_pack_wT_split(const float* __restrict__ W, unsigned short* __restrict__ Wt) {
  __shared__ float tile[32][33];
  int tx = threadIdx.x & 31, ty = threadIdx.x >> 5;    // ty in [0,8)
  int kb = blockIdx.x * 32, nb = blockIdx.y * 32;
#pragma unroll
  for (int i = 0; i < 4; ++i)
    tile[ty + 8 * i][tx] = W[(size_t)(kb + ty + 8 * i) * 1024 + nb + tx];
  __syncthreads();
#pragma unroll
  for (int i = 0; i < 4; ++i) {
    int n = nb + ty + 8 * i;
    int k = kb + tx;
    float x = tile[tx][ty + 8 * i];
    unsigned short h = f2bf(x);
    unsigned short l = f2bf(x - bf2f(h));
    unsigned short* base = Wt + (size_t)n * K3;
    base[k] = h;
    base[1024 + k] = l;
    base[2048 + k] = h;
  }
}

// ---------------- pack W (1024x1024) -> transposed plain bf16 (1024 x 1024) ----------------
__global__ void k_pack_wT_plain(const float* __restrict__ W, unsigned short* __restrict__ Wt) {
  __shared__ float tile[32][33];
  int tx = threadIdx.x & 31, ty = threadIdx.x >> 5;
  int kb = blockIdx.x * 32, nb = blockIdx.y * 32;
#pragma unroll
  for (int i = 0; i < 4; ++i)
    tile[ty + 8 * i][tx] = W[(size_t)(kb + ty + 8 * i) * 1024 + nb + tx];
  __syncthreads();
#pragma unroll
  for (int i = 0; i < 4; ++i) {
    int n = nb + ty + 8 * i;
    int k = kb + tx;
    Wt[(size_t)n * 1024 + k] = f2bf(tile[tx][ty + 8 * i]);
  }
}

// ---------------- pack Y (N x 1024 f32) -> per-head (bh, l, 64) bf16, optional scale ----------------
__global__ void k_pack_head(const float* __restrict__ Y, unsigned short* __restrict__ P, float scale) {
  int t = blockIdx.x * 256 + threadIdx.x;
  int idx = t << 3;
  int m = idx >> 10, n = idx & 1023;
  int b = m >> 11, l = m & 2047;
  int h = n >> 6, d0 = n & 63;
  const float4* src = reinterpret_cast<const float4*>(Y + idx);
  float4 a = src[0], c = src[1];
  float xs[8] = {a.x, a.y, a.z, a.w, c.x, c.y, c.z, c.w};
  u16x8 hi;
#pragma unroll
  for (int j = 0; j < 8; ++j) hi[j] = f2bf(xs[j] * scale);
  size_t base = ((size_t)(b * 16 + h) * 2048 + l) * 64 + d0;
  *reinterpret_cast<u16x8*>(P + base) = hi;
}

// ---------------- pack V: Y (N x 1024 f32) -> gated transposed per-head (bh, d, L) bf16 ----------------
__global__ void k_pack_v(const float* __restrict__ Y, const float* __restrict__ gate,
                         unsigned short* __restrict__ Vt) {
  __shared__ float tile[32][65];
  int bh = blockIdx.y;
  int b = bh >> 4, h = bh & 15;
  int l0 = blockIdx.x * 32;
  int tx = threadIdx.x & 63, ty = threadIdx.x >> 6;   // read: tx = d, ty+4i = l-local
#pragma unroll
  for (int i = 0; i < 8; ++i) {
    int ll = ty + 4 * i;
    float g = gate[b * 2048 + l0 + ll];
    tile[ll][tx] = Y[(size_t)(b * 2048 + l0 + ll) * 1024 + h * 64 + tx] * g;
  }
  __syncthreads();
  int lx = threadIdx.x & 31, dy = threadIdx.x >> 5;   // write: lx = l-local, d = dy + 8i
#pragma unroll
  for (int i = 0; i < 8; ++i) {
    int d = dy + 8 * i;
    Vt[((size_t)bh * 64 + d) * 2048 + l0 + lx] = f2bf(tile[lx][d]);
  }
}

// ---------------- GEMM: C(Mx1024 f32) = A(MxKD bf16) * Bt(1024xKD bf16)^T + bias ----------------
// BM=64, BN=128, BK=64. 4 waves in 2x2, each wave 32x64 (2x4 fragments of 16x16x32 MFMA).
template <int KD>
__global__ __launch_bounds__(256) void k_gemm(const unsigned short* __restrict__ A,
                                              const unsigned short* __restrict__ Bt,
                                              const float* __restrict__ bias,
                                              float* __restrict__ C) {
  __shared__ unsigned short sA[64 * 64];    // 8KB, rows 128B, XOR-swizzled
  __shared__ unsigned short sB[128 * 64];   // 16KB
  const int tid = threadIdx.x;
  const int lane = tid & 63, wave = tid >> 6;
  const int l15 = lane & 15, l4 = lane >> 4;
  const int wr = wave >> 1, wc = wave & 1;
  const int m0 = blockIdx.x * 64, n0 = blockIdx.y * 128;

  const f32x4 zero4 = {0.f, 0.f, 0.f, 0.f};
  f32x4 acc[2][4];
#pragma unroll
  for (int i = 0; i < 2; ++i)
#pragma unroll
    for (int j = 0; j < 4; ++j) acc[i][j] = zero4;

  for (int k0 = 0; k0 < KD; k0 += 64) {
    uint4 ra[2], rb[4];
#pragma unroll
    for (int i = 0; i < 2; ++i) {
      int id = tid + 256 * i;
      int row = id >> 3, c = id & 7;
      ra[i] = *reinterpret_cast<const uint4*>(A + (size_t)(m0 + row) * KD + k0 + c * 8);
    }
#pragma unroll
    for (int i = 0; i < 4; ++i) {
      int id = tid + 256 * i;
      int row = id >> 3, c = id & 7;
      rb[i] = *reinterpret_cast<const uint4*>(Bt + (size_t)(n0 + row) * KD + k0 + c * 8);
    }
    __syncthreads();   // previous iteration's LDS reads complete
#pragma unroll
    for (int i = 0; i < 2; ++i) {
      int id = tid + 256 * i;
      int row = id >> 3, c = id & 7;
      *reinterpret_cast<uint4*>(reinterpret_cast<char*>(sA) + row * 128 + ((c ^ (row & 7)) * 16)) = ra[i];
    }
#pragma unroll
    for (int i = 0; i < 4; ++i) {
      int id = tid + 256 * i;
      int row = id >> 3, c = id & 7;
      *reinterpret_cast<uint4*>(reinterpret_cast<char*>(sB) + row * 128 + ((c ^ (row & 7)) * 16)) = rb[i];
    }
    __syncthreads();
#pragma unroll
    for (int kc = 0; kc < 2; ++kc) {
      bf16x8 af[2], bfrag[4];
#pragma unroll
      for (int f = 0; f < 2; ++f) {
        int r = wr * 32 + f * 16 + l15;
        af[f] = *reinterpret_cast<const bf16x8*>(
            reinterpret_cast<const char*>(sA) + r * 128 + (((kc * 4 + l4) ^ (r & 7)) * 16));
      }
#pragma unroll
      for (int f = 0; f < 4; ++f) {
        int r = wc * 64 + f * 16 + l15;
        bfrag[f] = *reinterpret_cast<const bf16x8*>(
            reinterpret_cast<const char*>(sB) + r * 128 + (((kc * 4 + l4) ^ (r & 7)) * 16));
      }
#pragma unroll
      for (int fm = 0; fm < 2; ++fm)
#pragma unroll
        for (int fn = 0; fn < 4; ++fn)
          acc[fm][fn] = __builtin_amdgcn_mfma_f32_16x16x32_bf16(af[fm], bfrag[fn], acc[fm][fn], 0, 0, 0);
    }
  }
#pragma unroll
  for (int fm = 0; fm < 2; ++fm)
#pragma unroll
    for (int fn = 0; fn < 4; ++fn) {
      int col = n0 + wc * 64 + fn * 16 + l15;
      float bv = bias[col];
#pragma unroll
      for (int j = 0; j < 4; ++j) {
        int row = m0 + wr * 32 + fm * 16 + l4 * 4 + j;
        C[(size_t)row * 1024 + col] = acc[fm][fn][j] + bv;
      }
    }
}

// ---------------- flash attention (per (b,h), 128 q-rows per block, KV tiles of 64) ----------------
__global__ __launch_bounds__(256) void k_flash(const unsigned short* __restrict__ Qp,
                                               const unsigned short* __restrict__ Kp,
                                               const unsigned short* __restrict__ Vt,
                                               float* __restrict__ O) {
  __shared__ unsigned short sK[64 * 64];    // 8KB
  __shared__ unsigned short sV[64 * 64];    // 8KB (V^T: rows = d, cols = keys)
  __shared__ unsigned short sP[4][32 * 64]; // 16KB, per-wave P tile
  const int tid = threadIdx.x;
  const int lane = tid & 63, wave = tid >> 6;
  const int l15 = lane & 15, l4 = lane >> 4;
  const int bh = blockIdx.x;
  const int q0 = blockIdx.y * 128;
  const int b = bh >> 4, h = bh & 15;
  const size_t hBase = (size_t)bh * 2048 * 64;   // same for Q/K (l,d) and V^T (d,l)

  // Q fragments held in registers (Q pre-scaled by 1/8)
  bf16x8 qf[2][2];
#pragma unroll
  for (int fr = 0; fr < 2; ++fr) {
    int row = q0 + wave * 32 + fr * 16 + l15;
#pragma unroll
    for (int kc = 0; kc < 2; ++kc)
      qf[fr][kc] = *reinterpret_cast<const bf16x8*>(Qp + hBase + (size_t)row * 64 + kc * 32 + l4 * 8);
  }

  const f32x4 zero4 = {0.f, 0.f, 0.f, 0.f};
  f32x4 accO[2][4];
  float mrun[2][4], lrun[2][4];
#pragma unroll
  for (int fr = 0; fr < 2; ++fr)
#pragma unroll
    for (int j = 0; j < 4; ++j) {
      mrun[fr][j] = -3.0e38f;
      lrun[fr][j] = 0.f;
    }
#pragma unroll
  for (int fr = 0; fr < 2; ++fr)
#pragma unroll
    for (int fd = 0; fd < 4; ++fd) accO[fr][fd] = zero4;

  for (int kv0 = 0; kv0 < 2048; kv0 += 64) {
    // stage K tile (keys x 64) and V^T tile (d x keys)
    uint4 rk[2], rv[2];
#pragma unroll
    for (int i = 0; i < 2; ++i) {
      int id = tid + 256 * i;
      int row = id >> 3, c = id & 7;
      rk[i] = *reinterpret_cast<const uint4*>(Kp + hBase + (size_t)(kv0 + row) * 64 + c * 8);
      rv[i] = *reinterpret_cast<const uint4*>(Vt + hBase + (size_t)row * 2048 + kv0 + c * 8);
    }
    __syncthreads();
#pragma unroll
    for (int i = 0; i < 2; ++i) {
      int id = tid + 256 * i;
      int row = id >> 3, c = id & 7;
      int off = row * 128 + ((c ^ (row & 7)) * 16);
      *reinterpret_cast<uint4*>(reinterpret_cast<char*>(sK) + off) = rk[i];
      *reinterpret_cast<uint4*>(reinterpret_cast<char*>(sV) + off) = rv[i];
    }
    __syncthreads();

    // S = Q K^T (rows q, cols keys): C-frag row=(l4*4+j), col=l15
    f32x4 s[2][4];
#pragma unroll
    for (int fr = 0; fr < 2; ++fr)
#pragma unroll
      for (int fk = 0; fk < 4; ++fk) s[fr][fk] = zero4;
#pragma unroll
    for (int kc = 0; kc < 2; ++kc) {
      bf16x8 kf[4];
#pragma unroll
      for (int fk = 0; fk < 4; ++fk) {
        int r = fk * 16 + l15;
        kf[fk] = *reinterpret_cast<const bf16x8*>(
            reinterpret_cast<const char*>(sK) + r * 128 + (((kc * 4 + l4) ^ (r & 7)) * 16));
      }
#pragma unroll
      for (int fr = 0; fr < 2; ++fr)
#pragma unroll
        for (int fk = 0; fk < 4; ++fk)
          s[fr][fk] = __builtin_amdgcn_mfma_f32_16x16x32_bf16(qf[fr][kc], kf[fk], s[fr][fk], 0, 0, 0);
    }

    // online softmax; rows r = fr*16 + l4*4 + j live on the 16 lanes sharing l4
    float alpha[2][4];
#pragma unroll
    for (int fr = 0; fr < 2; ++fr) {
#pragma unroll
      for (int j = 0; j < 4; ++j) {
        float pm = fmaxf(fmaxf(s[fr][0][j], s[fr][1][j]), fmaxf(s[fr][2][j], s[fr][3][j]));
#pragma unroll
        for (int off = 1; off < 16; off <<= 1) pm = fmaxf(pm, __shfl_xor(pm, off));
        float mo = mrun[fr][j];
        float mn = fmaxf(mo, pm);
        float a = __expf(mo - mn);
        float ps = 0.f;
#pragma unroll
        for (int fk = 0; fk < 4; ++fk) {
          float p = __expf(s[fr][fk][j] - mn);
          s[fr][fk][j] = p;
          ps += p;
        }
#pragma unroll
        for (int off = 1; off < 16; off <<= 1) ps += __shfl_xor(ps, off);
        lrun[fr][j] = lrun[fr][j] * a + ps;
        mrun[fr][j] = mn;
        alpha[fr][j] = a;
      }
    }
#pragma unroll
    for (int fr = 0; fr < 2; ++fr)
#pragma unroll
      for (int fd = 0; fd < 4; ++fd)
#pragma unroll
        for (int j = 0; j < 4; ++j) accO[fr][fd][j] *= alpha[fr][j];

    // write P (bf16) to this wave's LDS region (C-layout -> A-layout round trip)
    char* pbase = reinterpret_cast<char*>(&sP[wave][0]);
#pragma unroll
    for (int fr = 0; fr < 2; ++fr)
#pragma unroll
      for (int fk = 0; fk < 4; ++fk)
#pragma unroll
        for (int j = 0; j < 4; ++j) {
          int r = fr * 16 + l4 * 4 + j;
          int key2 = (fk * 16 + l15) * 2;
          *reinterpret_cast<unsigned short*>(pbase + r * 128 + (key2 ^ ((r & 7) << 4))) =
              f2bf(s[fr][fk][j]);
        }

    // O += P * V  (A = P rows q, B = V^T rows d)
#pragma unroll
    for (int kc = 0; kc < 2; ++kc) {
      bf16x8 pf[2], vf[4];
#pragma unroll
      for (int fr = 0; fr < 2; ++fr) {
        int r = fr * 16 + l15;
        pf[fr] = *reinterpret_cast<const bf16x8*>(
            pbase + r * 128 + (((kc * 4 + l4) ^ (r & 7)) * 16));
      }
#pragma unroll
      for (int fd = 0; fd < 4; ++fd) {
        int r = fd * 16 + l15;
        vf[fd] = *reinterpret_cast<const bf16x8*>(
            reinterpret_cast<const char*>(sV) + r * 128 + (((kc * 4 + l4) ^ (r & 7)) * 16));
      }
#pragma unroll
      for (int fr = 0; fr < 2; ++fr)
#pragma unroll
        for (int fd = 0; fd < 4; ++fd)
          accO[fr][fd] = __builtin_amdgcn_mfma_f32_16x16x32_bf16(pf[fr], vf[fd], accO[fr][fd], 0, 0, 0);
    }
  }

  // epilogue: divide by softmax denom, write (b, l, h*64+d)
#pragma unroll
  for (int fr = 0; fr < 2; ++fr)
#pragma unroll
    for (int fd = 0; fd < 4; ++fd) {
      int col = h * 64 + fd * 16 + l15;
#pragma unroll
      for (int j = 0; j < 4; ++j) {
        int qrow = q0 + wave * 32 + fr * 16 + l4 * 4 + j;
        O[(size_t)(b * 2048 + qrow) * 1024 + col] = accO[fr][fd][j] / lrun[fr][j];
      }
    }
}

extern "C" void kernel_launch(void* const* d_in, const int* in_sizes, int n_in,
                              void* d_out, int out_size, void* d_ws, size_t ws_size,
                              hipStream_t stream) {
  const float* q_x = (const float*)d_in[0];
  const float* k_x = (const float*)d_in[1];
  const float* v_x = (const float*)d_in[2];
  const float* E   = (const float*)d_in[3];
  const float* Wq  = (const float*)d_in[4];
  const float* bq  = (const float*)d_in[5];
  const float* Wk  = (const float*)d_in[6];
  const float* bk  = (const float*)d_in[7];
  const float* Wv  = (const float*)d_in[8];
  const float* bv  = (const float*)d_in[9];
  const float* Wo  = (const float*)d_in[10];
  const float* bo  = (const float*)d_in[11];
  float* out = (float*)d_out;

  char* w = (char*)d_ws;
  unsigned short* Wtq = (unsigned short*)(w + 0);          // 1024x3072 bf16 = 6291456 B
  unsigned short* Wtk = (unsigned short*)(w + 6291456);    // 6291456
  unsigned short* Wtv = (unsigned short*)(w + 12582912);   // 1024x1024 bf16 = 2097152
  unsigned short* Wto = (unsigned short*)(w + 14680064);   // 2097152
  unsigned short* Xp  = (unsigned short*)(w + 16777216);   // up to 4096x3072 bf16 = 25165824
  unsigned short* Qp  = (unsigned short*)(w + 41943040);   // 32x2048x64 bf16 = 8388608
  unsigned short* Kpp = (unsigned short*)(w + 50331648);   // 8388608
  unsigned short* Vtp = (unsigned short*)(w + 58720256);   // 8388608
  float*          Ytmp = (float*)(w + 67108864);           // 4096x1024 f32 = 16777216
  float*          gate = (float*)(w + 83886080);           // 16384
  // total ~80 MB

  k_gate<<<16, 256, 0, stream>>>(E, gate);

  k_pack_wT_split<<<dim3(32, 32), 256, 0, stream>>>(Wq, Wtq);
  k_pack_wT_split<<<dim3(32, 32), 256, 0, stream>>>(Wk, Wtk);
  k_pack_wT_plain<<<dim3(32, 32), 256, 0, stream>>>(Wv, Wtv);
  k_pack_wT_plain<<<dim3(32, 32), 256, 0, stream>>>(Wo, Wto);

  // Q projection (bf16x3 split), then per-head layout with 1/sqrt(Dh) folded in
  k_pack_split<<<2048, 256, 0, stream>>>(q_x, Xp);
  k_gemm<3072><<<dim3(64, 8), 256, 0, stream>>>(Xp, Wtq, bq, Ytmp);
  k_pack_head<<<2048, 256, 0, stream>>>(Ytmp, Qp, 0.125f);

  // K projection (split)
  k_pack_split<<<2048, 256, 0, stream>>>(k_x, Xp);
  k_gemm<3072><<<dim3(64, 8), 256, 0, stream>>>(Xp, Wtk, bk, Ytmp);
  k_pack_head<<<2048, 256, 0, stream>>>(Ytmp, Kpp, 1.0f);

  // V projection (plain bf16), gate folded into V rows, stored transposed per head
  k_pack_plain<<<2048, 256, 0, stream>>>(v_x, Xp);
  k_gemm<1024><<<dim3(64, 8), 256, 0, stream>>>(Xp, Wtv, bv, Ytmp);
  k_pack_v<<<dim3(64, 32), 256, 0, stream>>>(Ytmp, gate, Vtp);

  // attention
  k_flash<<<dim3(32, 16), 256, 0, stream>>>(Qp, Kpp, Vtp, Ytmp);

  // output projection (plain bf16)
  k_pack_plain<<<2048, 256, 0, stream>>>(Ytmp, Xp);
  k_gemm<1024><<<dim3(64, 8), 256, 0, stream>>>(Xp, Wto, bo, out);
}

// Round 2
// 296.940 us; speedup vs baseline: 2.1313x; 2.1313x over previous
//
#include <hip/hip_runtime.h>

typedef __attribute__((ext_vector_type(8))) short bf16x8;
typedef __attribute__((ext_vector_type(8))) unsigned short u16x8;
typedef __attribute__((ext_vector_type(4))) float f32x4;

#define DEVI static __device__ __forceinline__

// async global->LDS, 16B per lane; gp per-lane, lp wave-uniform
typedef const __attribute__((address_space(1))) void cglobal_void;
typedef __attribute__((address_space(3))) void lds_void;
#define GLD16(gp, lp) __builtin_amdgcn_global_load_lds((cglobal_void*)(gp), (lds_void*)(lp), 16, 0, 0)

// Problem constants: B=2, L=2048, D=1024, H=16, Dh=64
constexpr int K3 = 3072;      // tripled K for split GEMMs

DEVI unsigned short f2bf(float x) {
  unsigned int u = __builtin_bit_cast(unsigned int, x);
  u += 0x7fffu + ((u >> 16) & 1u);   // round-to-nearest-even
  return (unsigned short)(u >> 16);
}
DEVI float bf2f(unsigned short v) {
  unsigned int u = ((unsigned int)v) << 16;
  return __builtin_bit_cast(float, u);
}

// ---------------- gate: sigmoid((mean|E| - 0.1)*10) per (b,l) key ----------------
__global__ void k_gate(const float* __restrict__ E, float* __restrict__ gate) {
  int i = blockIdx.x * 256 + threadIdx.x;           // 0..4095
  const float4* e = reinterpret_cast<const float4*>(E);
  float4 a = e[i * 2], b = e[i * 2 + 1];
  float s = fabsf(a.x) + fabsf(a.y) + fabsf(a.z) + fabsf(a.w)
          + fabsf(b.x) + fabsf(b.y) + fabsf(b.z) + fabsf(b.w);
  float en = s * 0.125f;
  gate[i] = 1.0f / (1.0f + __expf(-10.0f * (en - 0.1f)));
}

// ---------------- pack X (4096 x 1024 f32) -> [hi|hi|lo] (4096 x 3072 bf16) ----------------
__global__ void k_pack_split(const float* __restrict__ X, unsigned short* __restrict__ Xp) {
  int t = blockIdx.x * 256 + threadIdx.x;
  int idx = t << 3;
  int m = idx >> 10, k = idx & 1023;
  const float4* src = reinterpret_cast<const float4*>(X + idx);
  float4 a = src[0], b = src[1];
  float xs[8] = {a.x, a.y, a.z, a.w, b.x, b.y, b.z, b.w};
  u16x8 hi, lo;
#pragma unroll
  for (int j = 0; j < 8; ++j) {
    unsigned short h = f2bf(xs[j]);
    hi[j] = h;
    lo[j] = f2bf(xs[j] - bf2f(h));
  }
  unsigned short* base = Xp + (size_t)m * K3 + k;
  *reinterpret_cast<u16x8*>(base) = hi;
  *reinterpret_cast<u16x8*>(base + 1024) = hi;
  *reinterpret_cast<u16x8*>(base + 2048) = lo;
}

// ---------------- pack X (N x 1024 f32) -> plain bf16 (N x 1024) ----------------
__global__ void k_pack_plain(const float* __restrict__ X, unsigned short* __restrict__ Xp) {
  int t = blockIdx.x * 256 + threadIdx.x;
  int idx = t << 3;
  const float4* src = reinterpret_cast<const float4*>(X + idx);
  float4 a = src[0], b = src[1];
  float xs[8] = {a.x, a.y, a.z, a.w, b.x, b.y, b.z, b.w};
  u16x8 hi;
#pragma unroll
  for (int j = 0; j < 8; ++j) hi[j] = f2bf(xs[j]);
  *reinterpret_cast<u16x8*>(Xp + idx) = hi;
}

// ---------------- pack W (1024x1024) -> transposed split (1024 x 3072) [hi|lo|hi] ----------------
__global__ void k_pack_wT_split(const float* __restrict__ W, unsigned short* __restrict__ Wt) {
  __shared__ float tile[32][33];
  int tx = threadIdx.x & 31, ty = threadIdx.x >> 5;    // ty in [0,8)
  int kb = blockIdx.x * 32, nb = blockIdx.y * 32;
#pragma unroll
  for (int i = 0; i < 4; ++i)
    tile[ty + 8 * i][tx] = W[(size_t)(kb + ty + 8 * i) * 1024 + nb + tx];
  __syncthreads();
#pragma unroll
  for (int i = 0; i < 4; ++i) {
    int n = nb + ty + 8 * i;
    int k = kb + tx;
    float x = tile[tx][ty + 8 * i];
    unsigned short h = f2bf(x);
    unsigned short l = f2bf(x - bf2f(h));
    unsigned short* base = Wt + (size_t)n * K3;
    base[k] = h;
    base[1024 + k] = l;
    base[2048 + k] = h;
  }
}

// ---------------- pack W (1024x1024) -> transposed plain bf16 (1024 x 1024) ----------------
__global__ void k_pack_wT_plain(const float* __restrict__ W, unsigned short* __restrict__ Wt) {
  __shared__ float tile[32][33];
  int tx = threadIdx.x & 31, ty = threadIdx.x >> 5;
  int kb = blockIdx.x * 32, nb = blockIdx.y * 32;
#pragma unroll
  for (int i = 0; i < 4; ++i)
    tile[ty + 8 * i][tx] = W[(size_t)(kb + ty + 8 * i) * 1024 + nb + tx];
  __syncthreads();
#pragma unroll
  for (int i = 0; i < 4; ++i) {
    int n = nb + ty + 8 * i;
    int k = kb + tx;
    Wt[(size_t)n * 1024 + k] = f2bf(tile[tx][ty + 8 * i]);
  }
}

// ---------------- pack V: Y (N x 1024 f32) -> gated transposed per-head (bh, d, L) bf16 ----------------
__global__ void k_pack_v(const float* __restrict__ Y, const float* __restrict__ gate,
                         unsigned short* __restrict__ Vt) {
  __shared__ float tile[32][65];
  int bh = blockIdx.y;
  int b = bh >> 4, h = bh & 15;
  int l0 = blockIdx.x * 32;
  int tx = threadIdx.x & 63, ty = threadIdx.x >> 6;   // read: tx = d, ty+4i = l-local
#pragma unroll
  for (int i = 0; i < 8; ++i) {
    int ll = ty + 4 * i;
    float g = gate[b * 2048 + l0 + ll];
    tile[ll][tx] = Y[(size_t)(b * 2048 + l0 + ll) * 1024 + h * 64 + tx] * g;
  }
  __syncthreads();
  int lx = threadIdx.x & 31, dy = threadIdx.x >> 5;   // write: lx = l-local, d = dy + 8i
#pragma unroll
  for (int i = 0; i < 8; ++i) {
    int d = dy + 8 * i;
    Vt[((size_t)bh * 64 + d) * 2048 + l0 + lx] = f2bf(tile[lx][d]);
  }
}

// ---------------- GEMM main loop: 128x128 tile, BK=64, global_load_lds staging ----------------
// LDS layout: sA/sB [128 rows][8 chunks of 16B], linear dest; source chunk pre-swizzled c^(r&7)
// so that a ds_read at chunk q^(r&7) yields global chunk q (conflict-free, <=2-way).
template <int KD>
DEVI void gemm_tile(const unsigned short* __restrict__ A,
                    const unsigned short* __restrict__ Bt,
                    unsigned short* sA, unsigned short* sB,
                    int m0, int n0, int tid, f32x4 acc[4][4]) {
  const int lane = tid & 63;
  const int l15 = lane & 15, l4 = lane >> 4;
  const int wave = tid >> 6;
  const int wr = wave >> 1, wc = wave & 1;
  const int wofs = (tid & 192) * 16;       // wave*1024 bytes: wave-uniform LDS base offset

  for (int k0 = 0; k0 < KD; k0 += 64) {
    __syncthreads();    // all waves done reading previous tile
#pragma unroll
    for (int i = 0; i < 4; ++i) {
      int id = i * 256 + tid;
      int r = id >> 3, c = id & 7;
      const unsigned short* gpA = A + (size_t)(m0 + r) * KD + k0 + ((c ^ (r & 7)) << 3);
      GLD16(gpA, (char*)sA + i * 4096 + wofs);
    }
#pragma unroll
    for (int i = 0; i < 4; ++i) {
      int id = i * 256 + tid;
      int r = id >> 3, c = id & 7;
      const unsigned short* gpB = Bt + (size_t)(n0 + r) * KD + k0 + ((c ^ (r & 7)) << 3);
      GLD16(gpB, (char*)sB + i * 4096 + wofs);
    }
    __syncthreads();    // compiler drains vmcnt(0) before barrier -> tiles ready
#pragma unroll
    for (int kc = 0; kc < 2; ++kc) {
      bf16x8 af[4], bfr[4];
#pragma unroll
      for (int f = 0; f < 4; ++f) {
        int r = wr * 64 + f * 16 + l15;
        af[f] = *reinterpret_cast<const bf16x8*>(
            reinterpret_cast<const char*>(sA) + r * 128 + (((kc * 4 + l4) ^ (r & 7)) * 16));
      }
#pragma unroll
      for (int f = 0; f < 4; ++f) {
        int r = wc * 64 + f * 16 + l15;
        bfr[f] = *reinterpret_cast<const bf16x8*>(
            reinterpret_cast<const char*>(sB) + r * 128 + (((kc * 4 + l4) ^ (r & 7)) * 16));
      }
#pragma unroll
      for (int fm = 0; fm < 4; ++fm)
#pragma unroll
        for (int fn = 0; fn < 4; ++fn)
          acc[fm][fn] = __builtin_amdgcn_mfma_f32_16x16x32_bf16(af[fm], bfr[fn], acc[fm][fn], 0, 0, 0);
    }
  }
}

// ---------------- fused Q+K projection GEMM (M=8192 stacked), bf16 per-head epilogue ----------------
__global__ __launch_bounds__(256) void k_gemm_qk(const unsigned short* __restrict__ A,
                                                 const unsigned short* __restrict__ WtQ,
                                                 const unsigned short* __restrict__ WtK,
                                                 const float* __restrict__ bq,
                                                 const float* __restrict__ bk,
                                                 unsigned short* __restrict__ Qp,
                                                 unsigned short* __restrict__ Kp) {
  __shared__ unsigned short sA[128 * 64];   // 16KB
  __shared__ unsigned short sB[128 * 64];   // 16KB
  const int tid = threadIdx.x;
  const int lane = tid & 63, wave = tid >> 6;
  const int l15 = lane & 15, l4 = lane >> 4;
  const int wr = wave >> 1, wc = wave & 1;
  const int m0 = blockIdx.x * 128, n0 = blockIdx.y * 128;
  const bool isK = (m0 >= 4096);
  const unsigned short* Bt = isK ? WtK : WtQ;
  const float* bias = isK ? bk : bq;
  unsigned short* Out = isK ? Kp : Qp;
  const float scale = isK ? 1.0f : 0.125f;

  const f32x4 zero4 = {0.f, 0.f, 0.f, 0.f};
  f32x4 acc[4][4];
#pragma unroll
  for (int i = 0; i < 4; ++i)
#pragma unroll
    for (int j = 0; j < 4; ++j) acc[i][j] = zero4;

  gemm_tile<3072>(A, Bt, sA, sB, m0, n0, tid, acc);

#pragma unroll
  for (int fm = 0; fm < 4; ++fm)
#pragma unroll
    for (int fn = 0; fn < 4; ++fn) {
      int col = n0 + wc * 64 + fn * 16 + l15;
      int h = col >> 6, d = col & 63;
      float bv = bias[col];
#pragma unroll
      for (int j = 0; j < 4; ++j) {
        int rowg = m0 + wr * 64 + fm * 16 + l4 * 4 + j;
        int rowm = rowg & 4095;
        int b = rowm >> 11, l = rowm & 2047;
        float v = (acc[fm][fn][j] + bv) * scale;
        Out[(((size_t)(b * 16 + h) * 2048 + l) << 6) + d] = f2bf(v);
      }
    }
}

// ---------------- plain GEMM, f32 + bias epilogue (V proj, O proj) ----------------
template <int KD>
__global__ __launch_bounds__(256) void k_gemm_f32(const unsigned short* __restrict__ A,
                                                  const unsigned short* __restrict__ Bt,
                                                  const float* __restrict__ bias,
                                                  float* __restrict__ C) {
  __shared__ unsigned short sA[128 * 64];
  __shared__ unsigned short sB[128 * 64];
  const int tid = threadIdx.x;
  const int lane = tid & 63, wave = tid >> 6;
  const int l15 = lane & 15, l4 = lane >> 4;
  const int wr = wave >> 1, wc = wave & 1;
  const int m0 = blockIdx.x * 128, n0 = blockIdx.y * 128;

  const f32x4 zero4 = {0.f, 0.f, 0.f, 0.f};
  f32x4 acc[4][4];
#pragma unroll
  for (int i = 0; i < 4; ++i)
#pragma unroll
    for (int j = 0; j < 4; ++j) acc[i][j] = zero4;

  gemm_tile<KD>(A, Bt, sA, sB, m0, n0, tid, acc);

#pragma unroll
  for (int fm = 0; fm < 4; ++fm)
#pragma unroll
    for (int fn = 0; fn < 4; ++fn) {
      int col = n0 + wc * 64 + fn * 16 + l15;
      float bv = bias[col];
#pragma unroll
      for (int j = 0; j < 4; ++j) {
        int row = m0 + wr * 64 + fm * 16 + l4 * 4 + j;
        C[(size_t)row * 1024 + col] = acc[fm][fn][j] + bv;
      }
    }
}

// ---------------- flash attention (per (b,h), 128 q-rows per block, KV tiles of 64) ----------------
__global__ __launch_bounds__(256) void k_flash(const unsigned short* __restrict__ Qp,
                                               const unsigned short* __restrict__ Kp,
                                               const unsigned short* __restrict__ Vt,
                                               unsigned short* __restrict__ O) {
  __shared__ unsigned short sK[64 * 64];    // 8KB
  __shared__ unsigned short sV[64 * 64];    // 8KB (V^T: rows = d, cols = keys)
  __shared__ unsigned short sP[4][32 * 64]; // 16KB, per-wave P tile
  const int tid = threadIdx.x;
  const int lane = tid & 63, wave = tid >> 6;
  const int l15 = lane & 15, l4 = lane >> 4;
  const int bh = blockIdx.x;
  const int q0 = blockIdx.y * 128;
  const int b = bh >> 4, h = bh & 15;
  const size_t hBase = (size_t)bh * 2048 * 64;   // same for Q/K (l,d) and V^T (d,l)
  const int wofs = (tid & 192) * 16;             // wave-uniform LDS offset

  // Q fragments held in registers (Q pre-scaled by 1/8)
  bf16x8 qf[2][2];
#pragma unroll
  for (int fr = 0; fr < 2; ++fr) {
    int row = q0 + wave * 32 + fr * 16 + l15;
#pragma unroll
    for (int kc = 0; kc < 2; ++kc)
      qf[fr][kc] = *reinterpret_cast<const bf16x8*>(Qp + hBase + (size_t)row * 64 + kc * 32 + l4 * 8);
  }

  const f32x4 zero4 = {0.f, 0.f, 0.f, 0.f};
  f32x4 accO[2][4];
  float mrun[2][4], lrun[2][4];
#pragma unroll
  for (int fr = 0; fr < 2; ++fr)
#pragma unroll
    for (int j = 0; j < 4; ++j) {
      mrun[fr][j] = -3.0e38f;
      lrun[fr][j] = 0.f;
    }
#pragma unroll
  for (int fr = 0; fr < 2; ++fr)
#pragma unroll
    for (int fd = 0; fd < 4; ++fd) accO[fr][fd] = zero4;

  for (int kv0 = 0; kv0 < 2048; kv0 += 64) {
    __syncthreads();   // previous tile's LDS reads complete
#pragma unroll
    for (int i = 0; i < 2; ++i) {
      int id = i * 256 + tid;
      int r = id >> 3, c = id & 7;
      int sc = (c ^ (r & 7)) << 3;
      const unsigned short* gpK = Kp + hBase + (size_t)(kv0 + r) * 64 + sc;
      const unsigned short* gpV = Vt + hBase + (size_t)r * 2048 + kv0 + sc;
      GLD16(gpK, (char*)sK + i * 4096 + wofs);
      GLD16(gpV, (char*)sV + i * 4096 + wofs);
    }
    __syncthreads();   // tiles ready

    // S = Q K^T (rows q, cols keys): C-frag row=(l4*4+j), col=l15
    f32x4 s[2][4];
#pragma unroll
    for (int fr = 0; fr < 2; ++fr)
#pragma unroll
      for (int fk = 0; fk < 4; ++fk) s[fr][fk] = zero4;
#pragma unroll
    for (int kc = 0; kc < 2; ++kc) {
      bf16x8 kf[4];
#pragma unroll
      for (int fk = 0; fk < 4; ++fk) {
        int r = fk * 16 + l15;
        kf[fk] = *reinterpret_cast<const bf16x8*>(
            reinterpret_cast<const char*>(sK) + r * 128 + (((kc * 4 + l4) ^ (r & 7)) * 16));
      }
#pragma unroll
      for (int fr = 0; fr < 2; ++fr)
#pragma unroll
        for (int fk = 0; fk < 4; ++fk)
          s[fr][fk] = __builtin_amdgcn_mfma_f32_16x16x32_bf16(qf[fr][kc], kf[fk], s[fr][fk], 0, 0, 0);
    }

    // online softmax; rows r = fr*16 + l4*4 + j live on the 16 lanes sharing l4
    float alpha[2][4];
#pragma unroll
    for (int fr = 0; fr < 2; ++fr) {
#pragma unroll
      for (int j = 0; j < 4; ++j) {
        float pm = fmaxf(fmaxf(s[fr][0][j], s[fr][1][j]), fmaxf(s[fr][2][j], s[fr][3][j]));
#pragma unroll
        for (int off = 1; off < 16; off <<= 1) pm = fmaxf(pm, __shfl_xor(pm, off));
        float mo = mrun[fr][j];
        float mn = fmaxf(mo, pm);
        float a = __expf(mo - mn);
        float ps = 0.f;
#pragma unroll
        for (int fk = 0; fk < 4; ++fk) {
          float p = __expf(s[fr][fk][j] - mn);
          s[fr][fk][j] = p;
          ps += p;
        }
#pragma unroll
        for (int off = 1; off < 16; off <<= 1) ps += __shfl_xor(ps, off);
        lrun[fr][j] = lrun[fr][j] * a + ps;
        mrun[fr][j] = mn;
        alpha[fr][j] = a;
      }
    }
#pragma unroll
    for (int fr = 0; fr < 2; ++fr)
#pragma unroll
      for (int fd = 0; fd < 4; ++fd)
#pragma unroll
        for (int j = 0; j < 4; ++j) accO[fr][fd][j] *= alpha[fr][j];

    // write P (bf16) to this wave's LDS region (C-layout -> A-layout round trip)
    char* pbase = reinterpret_cast<char*>(&sP[wave][0]);
#pragma unroll
    for (int fr = 0; fr < 2; ++fr)
#pragma unroll
      for (int fk = 0; fk < 4; ++fk)
#pragma unroll
        for (int j = 0; j < 4; ++j) {
          int r = fr * 16 + l4 * 4 + j;
          int key2 = (fk * 16 + l15) * 2;
          *reinterpret_cast<unsigned short*>(pbase + r * 128 + (key2 ^ ((r & 7) << 4))) =
              f2bf(s[fr][fk][j]);
        }

    // O += P * V  (A = P rows q, B = V^T rows d)
#pragma unroll
    for (int kc = 0; kc < 2; ++kc) {
      bf16x8 pf[2], vf[4];
#pragma unroll
      for (int fr = 0; fr < 2; ++fr) {
        int r = fr * 16 + l15;
        pf[fr] = *reinterpret_cast<const bf16x8*>(
            pbase + r * 128 + (((kc * 4 + l4) ^ (r & 7)) * 16));
      }
#pragma unroll
      for (int fd = 0; fd < 4; ++fd) {
        int r = fd * 16 + l15;
        vf[fd] = *reinterpret_cast<const bf16x8*>(
            reinterpret_cast<const char*>(sV) + r * 128 + (((kc * 4 + l4) ^ (r & 7)) * 16));
      }
#pragma unroll
      for (int fr = 0; fr < 2; ++fr)
#pragma unroll
        for (int fd = 0; fd < 4; ++fd)
          accO[fr][fd] = __builtin_amdgcn_mfma_f32_16x16x32_bf16(pf[fr], vf[fd], accO[fr][fd], 0, 0, 0);
    }
  }

  // epilogue: divide by softmax denom, write bf16 (b, l, h*64+d)
#pragma unroll
  for (int fr = 0; fr < 2; ++fr)
#pragma unroll
    for (int fd = 0; fd < 4; ++fd) {
      int col = h * 64 + fd * 16 + l15;
#pragma unroll
      for (int j = 0; j < 4; ++j) {
        int qrow = q0 + wave * 32 + fr * 16 + l4 * 4 + j;
        O[(size_t)(b * 2048 + qrow) * 1024 + col] = f2bf(accO[fr][fd][j] / lrun[fr][j]);
      }
    }
}

extern "C" void kernel_launch(void* const* d_in, const int* in_sizes, int n_in,
                              void* d_out, int out_size, void* d_ws, size_t ws_size,
                              hipStream_t stream) {
  const float* q_x = (const float*)d_in[0];
  const float* k_x = (const float*)d_in[1];
  const float* v_x = (const float*)d_in[2];
  const float* E   = (const float*)d_in[3];
  const float* Wq  = (const float*)d_in[4];
  const float* bq  = (const float*)d_in[5];
  const float* Wk  = (const float*)d_in[6];
  const float* bk  = (const float*)d_in[7];
  const float* Wv  = (const float*)d_in[8];
  const float* bv  = (const float*)d_in[9];
  const float* Wo  = (const float*)d_in[10];
  const float* bo  = (const float*)d_in[11];
  float* out = (float*)d_out;

  char* w = (char*)d_ws;
  unsigned short* Wtq  = (unsigned short*)(w + 0);          // 1024x3072 bf16 = 6 MB
  unsigned short* Wtk  = (unsigned short*)(w + 6291456);    // 6 MB
  unsigned short* Wtv  = (unsigned short*)(w + 12582912);   // 2 MB
  unsigned short* Wto  = (unsigned short*)(w + 14680064);   // 2 MB
  unsigned short* Xqk  = (unsigned short*)(w + 16777216);   // 8192x3072 bf16 = 48 MB -> ends 67108864
  // region reuse after QK GEMM completes (stream-ordered):
  unsigned short* Xv   = (unsigned short*)(w + 16777216);   // 4096x1024 bf16 = 8 MB
  float*          Ytmp = (float*)(w + 25165824);            // 4096x1024 f32 = 16 MB
  unsigned short* Vtp  = (unsigned short*)(w + 41943040);   // 8 MB
  unsigned short* Obf  = (unsigned short*)(w + 50331648);   // 8 MB
  unsigned short* Qp   = (unsigned short*)(w + 67108864);   // 8 MB
  unsigned short* Kpp  = (unsigned short*)(w + 75497472);   // 8 MB
  float*          gate = (float*)(w + 83886080);            // 16 KB

  k_gate<<<16, 256, 0, stream>>>(E, gate);

  k_pack_wT_split<<<dim3(32, 32), 256, 0, stream>>>(Wq, Wtq);
  k_pack_wT_split<<<dim3(32, 32), 256, 0, stream>>>(Wk, Wtk);
  k_pack_wT_plain<<<dim3(32, 32), 256, 0, stream>>>(Wv, Wtv);
  k_pack_wT_plain<<<dim3(32, 32), 256, 0, stream>>>(Wo, Wto);

  // Q and K inputs packed (bf16x3 split) into one stacked A matrix (8192 x 3072)
  k_pack_split<<<2048, 256, 0, stream>>>(q_x, Xqk);
  k_pack_split<<<2048, 256, 0, stream>>>(k_x, Xqk + (size_t)4096 * 3072);

  // fused Q+K projection, per-head bf16 epilogue (Q scaled by 1/8)
  k_gemm_qk<<<dim3(64, 8), 256, 0, stream>>>(Xqk, Wtq, Wtk, bq, bk, Qp, Kpp);

  // V projection (plain bf16), then gate folded into V rows, stored transposed per head
  k_pack_plain<<<2048, 256, 0, stream>>>(v_x, Xv);
  k_gemm_f32<1024><<<dim3(32, 8), 256, 0, stream>>>(Xv, Wtv, bv, Ytmp);
  k_pack_v<<<dim3(64, 32), 256, 0, stream>>>(Ytmp, gate, Vtp);

  // attention -> bf16 (b,l,1024)
  k_flash<<<dim3(32, 16), 256, 0, stream>>>(Qp, Kpp, Vtp, Obf);

  // output projection
  k_gemm_f32<1024><<<dim3(32, 8), 256, 0, stream>>>(Obf, Wto, bo, out);
}

// Round 5
// 211.734 us; speedup vs baseline: 2.9889x; 1.4024x over previous
//
#include <hip/hip_runtime.h>

typedef __attribute__((ext_vector_type(8))) short bf16x8;
typedef __attribute__((ext_vector_type(8))) unsigned short u16x8;
typedef __attribute__((ext_vector_type(4))) float f32x4;

#define DEVI static __device__ __forceinline__

// async global->LDS, 16B per lane; gp per-lane, lp wave-uniform
typedef const __attribute__((address_space(1))) void cglobal_void;
typedef __attribute__((address_space(3))) void lds_void;
#define GLD16(gp, lp) __builtin_amdgcn_global_load_lds((cglobal_void*)(gp), (lds_void*)(lp), 16, 0, 0)

// Problem constants: B=2, L=2048, D=1024, H=16, Dh=64
constexpr int K3 = 3072;      // tripled K for split GEMMs

DEVI unsigned short f2bf(float x) {
  unsigned int u = __builtin_bit_cast(unsigned int, x);
  u += 0x7fffu + ((u >> 16) & 1u);   // round-to-nearest-even
  return (unsigned short)(u >> 16);
}
DEVI float bf2f(unsigned short v) {
  unsigned int u = ((unsigned int)v) << 16;
  return __builtin_bit_cast(float, u);
}
DEVI unsigned int pack2bf(float lo, float hi) {
  return (unsigned int)f2bf(lo) | ((unsigned int)f2bf(hi) << 16);
}

// ---------------- gate: sigmoid((mean|E| - 0.1)*10) per (b,l) key ----------------
__global__ void k_gate(const float* __restrict__ E, float* __restrict__ gate) {
  int i = blockIdx.x * 256 + threadIdx.x;           // 0..4095
  const float4* e = reinterpret_cast<const float4*>(E);
  float4 a = e[i * 2], b = e[i * 2 + 1];
  float s = fabsf(a.x) + fabsf(a.y) + fabsf(a.z) + fabsf(a.w)
          + fabsf(b.x) + fabsf(b.y) + fabsf(b.z) + fabsf(b.w);
  float en = s * 0.125f;
  gate[i] = 1.0f / (1.0f + __expf(-10.0f * (en - 0.1f)));
}

// ---------------- pack X (4096 x 1024 f32) -> [hi|hi|lo] (4096 x 3072 bf16) ----------------
__global__ void k_pack_split(const float* __restrict__ X, unsigned short* __restrict__ Xp) {
  int t = blockIdx.x * 256 + threadIdx.x;
  int idx = t << 3;
  int m = idx >> 10, k = idx & 1023;
  const float4* src = reinterpret_cast<const float4*>(X + idx);
  float4 a = src[0], b = src[1];
  float xs[8] = {a.x, a.y, a.z, a.w, b.x, b.y, b.z, b.w};
  u16x8 hi, lo;
#pragma unroll
  for (int j = 0; j < 8; ++j) {
    unsigned short h = f2bf(xs[j]);
    hi[j] = h;
    lo[j] = f2bf(xs[j] - bf2f(h));
  }
  unsigned short* base = Xp + (size_t)m * K3 + k;
  *reinterpret_cast<u16x8*>(base) = hi;
  *reinterpret_cast<u16x8*>(base + 1024) = hi;
  *reinterpret_cast<u16x8*>(base + 2048) = lo;
}

// ---------------- pack X (N x 1024 f32) -> plain bf16 (N x 1024) ----------------
__global__ void k_pack_plain(const float* __restrict__ X, unsigned short* __restrict__ Xp) {
  int t = blockIdx.x * 256 + threadIdx.x;
  int idx = t << 3;
  const float4* src = reinterpret_cast<const float4*>(X + idx);
  float4 a = src[0], b = src[1];
  float xs[8] = {a.x, a.y, a.z, a.w, b.x, b.y, b.z, b.w};
  u16x8 hi;
#pragma unroll
  for (int j = 0; j < 8; ++j) hi[j] = f2bf(xs[j]);
  *reinterpret_cast<u16x8*>(Xp + idx) = hi;
}

// ---------------- pack W (1024x1024) -> transposed split (1024 x 3072) [hi|lo|hi] ----------------
__global__ void k_pack_wT_split(const float* __restrict__ W, unsigned short* __restrict__ Wt) {
  __shared__ float tile[32][33];
  int tx = threadIdx.x & 31, ty = threadIdx.x >> 5;    // ty in [0,8)
  int kb = blockIdx.x * 32, nb = blockIdx.y * 32;
#pragma unroll
  for (int i = 0; i < 4; ++i)
    tile[ty + 8 * i][tx] = W[(size_t)(kb + ty + 8 * i) * 1024 + nb + tx];
  __syncthreads();
#pragma unroll
  for (int i = 0; i < 4; ++i) {
    int n = nb + ty + 8 * i;
    int k = kb + tx;
    float x = tile[tx][ty + 8 * i];
    unsigned short h = f2bf(x);
    unsigned short l = f2bf(x - bf2f(h));
    unsigned short* base = Wt + (size_t)n * K3;
    base[k] = h;
    base[1024 + k] = l;
    base[2048 + k] = h;
  }
}

// ---------------- pack W (1024x1024) -> transposed plain bf16 (1024 x 1024) ----------------
__global__ void k_pack_wT_plain(const float* __restrict__ W, unsigned short* __restrict__ Wt) {
  __shared__ float tile[32][33];
  int tx = threadIdx.x & 31, ty = threadIdx.x >> 5;
  int kb = blockIdx.x * 32, nb = blockIdx.y * 32;
#pragma unroll
  for (int i = 0; i < 4; ++i)
    tile[ty + 8 * i][tx] = W[(size_t)(kb + ty + 8 * i) * 1024 + nb + tx];
  __syncthreads();
#pragma unroll
  for (int i = 0; i < 4; ++i) {
    int n = nb + ty + 8 * i;
    int k = kb + tx;
    Wt[(size_t)n * 1024 + k] = f2bf(tile[tx][ty + 8 * i]);
  }
}

// ---------------- pack V: Y (N x 1024 f32) -> gated transposed per-head (bh, d, L) bf16 ----------------
__global__ void k_pack_v(const float* __restrict__ Y, const float* __restrict__ gate,
                         unsigned short* __restrict__ Vt) {
  __shared__ float tile[32][65];
  int bh = blockIdx.y;
  int b = bh >> 4, h = bh & 15;
  int l0 = blockIdx.x * 32;
  int tx = threadIdx.x & 63, ty = threadIdx.x >> 6;   // read: tx = d, ty+4i = l-local
#pragma unroll
  for (int i = 0; i < 8; ++i) {
    int ll = ty + 4 * i;
    float g = gate[b * 2048 + l0 + ll];
    tile[ll][tx] = Y[(size_t)(b * 2048 + l0 + ll) * 1024 + h * 64 + tx] * g;
  }
  __syncthreads();
  int lx = threadIdx.x & 31, dy = threadIdx.x >> 5;   // write: lx = l-local, d = dy + 8i
#pragma unroll
  for (int i = 0; i < 8; ++i) {
    int d = dy + 8 * i;
    Vt[((size_t)bh * 64 + d) * 2048 + l0 + lx] = f2bf(tile[lx][d]);
  }
}

// ---------------- GEMM main loop: 128x128 tile, BK=64, dbuf LDS + global_load_lds prefetch ----------------
// LDS: linear dest rows of 128B; source chunk pre-swizzled c^(r&7); ds_read at q^(r&7).
template <int KD>
DEVI void gemm_tile(const unsigned short* __restrict__ A,
                    const unsigned short* __restrict__ Bt,
                    unsigned short* sA0, unsigned short* sB0,
                    int m0, int n0, int tid, f32x4 acc[4][4]) {
  const int lane = tid & 63;
  const int l15 = lane & 15, l4 = lane >> 4;
  const int wave = tid >> 6;
  const int wr = wave >> 1, wc = wave & 1;
  const int wofs = (tid & 192) * 16;       // wave*1024 bytes: wave-uniform LDS base offset

  auto stage = [&](int buf, int k0) {
    unsigned short* dA = sA0 + buf * 8192;
    unsigned short* dB = sB0 + buf * 8192;
#pragma unroll
    for (int i = 0; i < 4; ++i) {
      int id = i * 256 + tid;
      int r = id >> 3, c = id & 7;
      GLD16(A + (size_t)(m0 + r) * KD + k0 + ((c ^ (r & 7)) << 3), (char*)dA + i * 4096 + wofs);
    }
#pragma unroll
    for (int i = 0; i < 4; ++i) {
      int id = i * 256 + tid;
      int r = id >> 3, c = id & 7;
      GLD16(Bt + (size_t)(n0 + r) * KD + k0 + ((c ^ (r & 7)) << 3), (char*)dB + i * 4096 + wofs);
    }
  };

  stage(0, 0);
  int cur = 0;
  for (int k0 = 0; k0 < KD; k0 += 64) {
    __syncthreads();   // drains vmcnt for tile k0; also protects buf cur^1 writes
    if (k0 + 64 < KD) stage(cur ^ 1, k0 + 64);
    const unsigned short* cA = sA0 + cur * 8192;
    const unsigned short* cB = sB0 + cur * 8192;
#pragma unroll
    for (int kc = 0; kc < 2; ++kc) {
      bf16x8 af[4], bfr[4];
#pragma unroll
      for (int f = 0; f < 4; ++f) {
        int r = wr * 64 + f * 16 + l15;
        af[f] = *reinterpret_cast<const bf16x8*>(
            reinterpret_cast<const char*>(cA) + r * 128 + (((kc * 4 + l4) ^ (r & 7)) * 16));
      }
#pragma unroll
      for (int f = 0; f < 4; ++f) {
        int r = wc * 64 + f * 16 + l15;
        bfr[f] = *reinterpret_cast<const bf16x8*>(
            reinterpret_cast<const char*>(cB) + r * 128 + (((kc * 4 + l4) ^ (r & 7)) * 16));
      }
#pragma unroll
      for (int fm = 0; fm < 4; ++fm)
#pragma unroll
        for (int fn = 0; fn < 4; ++fn)
          acc[fm][fn] = __builtin_amdgcn_mfma_f32_16x16x32_bf16(af[fm], bfr[fn], acc[fm][fn], 0, 0, 0);
    }
    cur ^= 1;
  }
}

// ---------------- fused Q+K projection GEMM (M=8192 stacked), bf16 per-head epilogue ----------------
// Q epilogue scale folds 1/sqrt(Dh) AND log2(e) so flash softmax runs in exp2 domain.
__global__ __launch_bounds__(256) void k_gemm_qk(const unsigned short* __restrict__ A,
                                                 const unsigned short* __restrict__ WtQ,
                                                 const unsigned short* __restrict__ WtK,
                                                 const float* __restrict__ bq,
                                                 const float* __restrict__ bk,
                                                 unsigned short* __restrict__ Qp,
                                                 unsigned short* __restrict__ Kp) {
  __shared__ unsigned short sA[2][128 * 64];   // 32KB
  __shared__ unsigned short sB[2][128 * 64];   // 32KB
  const int tid = threadIdx.x;
  const int lane = tid & 63, wave = tid >> 6;
  const int l15 = lane & 15, l4 = lane >> 4;
  const int wr = wave >> 1, wc = wave & 1;
  const int m0 = blockIdx.x * 128, n0 = blockIdx.y * 128;
  const bool isK = (m0 >= 4096);
  const unsigned short* Bt = isK ? WtK : WtQ;
  const float* bias = isK ? bk : bq;
  unsigned short* Out = isK ? Kp : Qp;
  const float scale = isK ? 1.0f : 0.18033688011112042f;  // 0.125 * log2(e)

  const f32x4 zero4 = {0.f, 0.f, 0.f, 0.f};
  f32x4 acc[4][4];
#pragma unroll
  for (int i = 0; i < 4; ++i)
#pragma unroll
    for (int j = 0; j < 4; ++j) acc[i][j] = zero4;

  gemm_tile<3072>(A, Bt, &sA[0][0], &sB[0][0], m0, n0, tid, acc);

#pragma unroll
  for (int fm = 0; fm < 4; ++fm)
#pragma unroll
    for (int fn = 0; fn < 4; ++fn) {
      int col = n0 + wc * 64 + fn * 16 + l15;
      int h = col >> 6, d = col & 63;
      float bv = bias[col];
#pragma unroll
      for (int j = 0; j < 4; ++j) {
        int rowg = m0 + wr * 64 + fm * 16 + l4 * 4 + j;
        int rowm = rowg & 4095;
        int b = rowm >> 11, l = rowm & 2047;
        float v = (acc[fm][fn][j] + bv) * scale;
        Out[(((size_t)(b * 16 + h) * 2048 + l) << 6) + d] = f2bf(v);
      }
    }
}

// ---------------- plain GEMM, f32 + bias epilogue (V proj, O proj) ----------------
template <int KD>
__global__ __launch_bounds__(256) void k_gemm_f32(const unsigned short* __restrict__ A,
                                                  const unsigned short* __restrict__ Bt,
                                                  const float* __restrict__ bias,
                                                  float* __restrict__ C) {
  __shared__ unsigned short sA[2][128 * 64];
  __shared__ unsigned short sB[2][128 * 64];
  const int tid = threadIdx.x;
  const int lane = tid & 63, wave = tid >> 6;
  const int l15 = lane & 15, l4 = lane >> 4;
  const int wr = wave >> 1, wc = wave & 1;
  const int m0 = blockIdx.x * 128, n0 = blockIdx.y * 128;

  const f32x4 zero4 = {0.f, 0.f, 0.f, 0.f};
  f32x4 acc[4][4];
#pragma unroll
  for (int i = 0; i < 4; ++i)
#pragma unroll
    for (int j = 0; j < 4; ++j) acc[i][j] = zero4;

  gemm_tile<KD>(A, Bt, &sA[0][0], &sB[0][0], m0, n0, tid, acc);

#pragma unroll
  for (int fm = 0; fm < 4; ++fm)
#pragma unroll
    for (int fn = 0; fn < 4; ++fn) {
      int col = n0 + wc * 64 + fn * 16 + l15;
      float bv = bias[col];
#pragma unroll
      for (int j = 0; j < 4; ++j) {
        int row = m0 + wr * 64 + fm * 16 + l4 * 4 + j;
        C[(size_t)row * 1024 + col] = acc[fm][fn][j] + bv;
      }
    }
}

// ---------------- flash attention, swapped-QK in-register softmax (exp2 domain) ----------------
// Per (b,h), 128 q-rows/block, 4 waves x 32q, KV tiles of 64, dbuf K/V staging.
// S^T = mfma(K,Q): lane holds S[k=fk*16+l4*4+j][q=fq*16+l15] -> row-reduce is in-lane.
__global__ __launch_bounds__(256) void k_flash(const unsigned short* __restrict__ Qp,
                                               const unsigned short* __restrict__ Kp,
                                               const unsigned short* __restrict__ Vt,
                                               unsigned short* __restrict__ O) {
  __shared__ unsigned short sK[2][64 * 64];   // 16KB
  __shared__ unsigned short sV[2][64 * 64];   // 16KB (V^T: rows=d, cols=keys)
  __shared__ unsigned short sP[4][32 * 64];   // 16KB, per-wave P tile (rows=q, cols=k)
  const int tid = threadIdx.x;
  const int lane = tid & 63, wave = tid >> 6;
  const int l15 = lane & 15, l4 = lane >> 4;
  const int bh = blockIdx.x;
  const int q0 = blockIdx.y * 128;
  const int b = bh >> 4, h = bh & 15;
  const size_t hBase = (size_t)bh * 2048 * 64;
  const int wofs = (tid & 192) * 16;          // wave-uniform LDS offset

  // Q fragments (B-operand): row=q (l15), elems kc*32 + l4*8..+7. Q pre-scaled by 0.125*log2e.
  bf16x8 qf[2][2];
#pragma unroll
  for (int fq = 0; fq < 2; ++fq) {
    int row = q0 + wave * 32 + fq * 16 + l15;
#pragma unroll
    for (int kc = 0; kc < 2; ++kc)
      qf[fq][kc] = *reinterpret_cast<const bf16x8*>(Qp + hBase + (size_t)row * 64 + kc * 32 + l4 * 8);
  }

  const f32x4 zero4 = {0.f, 0.f, 0.f, 0.f};
  f32x4 accO[2][4];
  float m[2], lp[2];              // running max (log2 units), per-lane PARTIAL denom
  m[0] = m[1] = -1.0e30f;
  lp[0] = lp[1] = 0.f;
#pragma unroll
  for (int fq = 0; fq < 2; ++fq)
#pragma unroll
    for (int fd = 0; fd < 4; ++fd) accO[fq][fd] = zero4;

  auto stage = [&](int buf, int kv0) {
#pragma unroll
    for (int i = 0; i < 2; ++i) {
      int id = i * 256 + tid;
      int r = id >> 3, c = id & 7;
      int sc = (c ^ (r & 7)) << 3;
      GLD16(Kp + hBase + (size_t)(kv0 + r) * 64 + sc, (char*)sK[buf] + i * 4096 + wofs);
      GLD16(Vt + hBase + (size_t)r * 2048 + kv0 + sc, (char*)sV[buf] + i * 4096 + wofs);
    }
  };

  char* pb = reinterpret_cast<char*>(&sP[wave][0]);
  stage(0, 0);
  int cur = 0;

  for (int kv0 = 0; kv0 < 2048; kv0 += 64) {
    __syncthreads();   // tile kv0 staged; all waves done reading buf cur^1
    if (kv0 + 64 < 2048) stage(cur ^ 1, kv0 + 64);

    // S^T = K Q^T: s[fk][fq], C row = k (l4*4+j), col = q (l15)
    f32x4 s[4][2];
#pragma unroll
    for (int fk = 0; fk < 4; ++fk)
#pragma unroll
      for (int fq = 0; fq < 2; ++fq) s[fk][fq] = zero4;
#pragma unroll
    for (int kc = 0; kc < 2; ++kc) {
      bf16x8 kf[4];
#pragma unroll
      for (int fk = 0; fk < 4; ++fk) {
        int r = fk * 16 + l15;
        kf[fk] = *reinterpret_cast<const bf16x8*>(
            reinterpret_cast<const char*>(sK[cur]) + r * 128 + (((kc * 4 + l4) ^ (r & 7)) * 16));
      }
#pragma unroll
      for (int fk = 0; fk < 4; ++fk)
#pragma unroll
        for (int fq = 0; fq < 2; ++fq)
          s[fk][fq] = __builtin_amdgcn_mfma_f32_16x16x32_bf16(kf[fk], qf[fq][kc], s[fk][fq], 0, 0, 0);
    }

    // per-lane tile max (16 values per q-column)
    float pmax[2];
#pragma unroll
    for (int fq = 0; fq < 2; ++fq) {
      float t0 = fmaxf(fmaxf(s[0][fq][0], s[0][fq][1]), fmaxf(s[0][fq][2], s[0][fq][3]));
      float t1 = fmaxf(fmaxf(s[1][fq][0], s[1][fq][1]), fmaxf(s[1][fq][2], s[1][fq][3]));
      float t2 = fmaxf(fmaxf(s[2][fq][0], s[2][fq][1]), fmaxf(s[2][fq][2], s[2][fq][3]));
      float t3 = fmaxf(fmaxf(s[3][fq][0], s[3][fq][1]), fmaxf(s[3][fq][2], s[3][fq][3]));
      pmax[fq] = fmaxf(fmaxf(t0, t1), fmaxf(t2, t3));
    }
    // defer-max: skip reduce+rescale while tile max stays within 8 (log2) of running max
    int defer = (pmax[0] <= m[0] + 8.f) && (pmax[1] <= m[1] + 8.f);
    if (!__all(defer)) {
#pragma unroll
      for (int fq = 0; fq < 2; ++fq) {
        float t = pmax[fq];
        t = fmaxf(t, __shfl_xor(t, 16));
        t = fmaxf(t, __shfl_xor(t, 32));
        float mn = fmaxf(m[fq], t);
        float a = exp2f(m[fq] - mn);
        lp[fq] *= a;
        m[fq] = mn;
#pragma unroll
        for (int j = 0; j < 4; ++j) {
          float aj = __shfl(a, (lane & 48) | (l4 * 4 + j), 64);
#pragma unroll
          for (int fd = 0; fd < 4; ++fd) accO[fq][fd][j] *= aj;
        }
      }
    }
    // p = 2^(s-m); accumulate per-lane partial denom; pack to LDS (rows=q, cols=k)
    // swizzle: pure XOR of bits 4-6 with (q&7) -> bijective, write/read consistent
#pragma unroll
    for (int fq = 0; fq < 2; ++fq) {
      int q = fq * 16 + l15;
      int qm = (q & 7) << 4;
      char* rowb = pb + q * 128;
      float sum = 0.f;
#pragma unroll
      for (int fk = 0; fk < 4; ++fk) {
        float p0 = exp2f(s[fk][fq][0] - m[fq]);
        float p1 = exp2f(s[fk][fq][1] - m[fq]);
        float p2 = exp2f(s[fk][fq][2] - m[fq]);
        float p3 = exp2f(s[fk][fq][3] - m[fq]);
        sum += (p0 + p1) + (p2 + p3);
        uint2 wv;
        wv.x = pack2bf(p0, p1);
        wv.y = pack2bf(p2, p3);
        *reinterpret_cast<uint2*>(rowb + ((fk * 32 + l4 * 8) ^ qm)) = wv;
      }
      lp[fq] += sum;
    }

    // O += P * V  (A = P rows q, B = V^T rows d)
#pragma unroll
    for (int kc = 0; kc < 2; ++kc) {
      bf16x8 pf[2], vf[4];
#pragma unroll
      for (int fq = 0; fq < 2; ++fq) {
        int q = fq * 16 + l15;
        int qm = (q & 7) << 4;
        pf[fq] = *reinterpret_cast<const bf16x8*>(
            pb + q * 128 + ((kc * 64 + l4 * 16) ^ qm));
      }
#pragma unroll
      for (int fd = 0; fd < 4; ++fd) {
        int r = fd * 16 + l15;
        vf[fd] = *reinterpret_cast<const bf16x8*>(
            reinterpret_cast<const char*>(sV[cur]) + r * 128 + (((kc * 4 + l4) ^ (r & 7)) * 16));
      }
#pragma unroll
      for (int fq = 0; fq < 2; ++fq)
#pragma unroll
        for (int fd = 0; fd < 4; ++fd)
          accO[fq][fd] = __builtin_amdgcn_mfma_f32_16x16x32_bf16(pf[fq], vf[fd], accO[fq][fd], 0, 0, 0);
    }
    cur ^= 1;
  }

  // epilogue: reduce partial denoms across l4, broadcast into C-row space, divide, store bf16
#pragma unroll
  for (int fq = 0; fq < 2; ++fq) {
    lp[fq] += __shfl_xor(lp[fq], 16);
    lp[fq] += __shfl_xor(lp[fq], 32);
  }
#pragma unroll
  for (int fq = 0; fq < 2; ++fq)
#pragma unroll
    for (int j = 0; j < 4; ++j) {
      float li = 1.0f / __shfl(lp[fq], (lane & 48) | (l4 * 4 + j), 64);
      int qrow = q0 + wave * 32 + fq * 16 + l4 * 4 + j;
#pragma unroll
      for (int fd = 0; fd < 4; ++fd) {
        int col = h * 64 + fd * 16 + l15;
        O[(size_t)(b * 2048 + qrow) * 1024 + col] = f2bf(accO[fq][fd][j] * li);
      }
    }
}

extern "C" void kernel_launch(void* const* d_in, const int* in_sizes, int n_in,
                              void* d_out, int out_size, void* d_ws, size_t ws_size,
                              hipStream_t stream) {
  const float* q_x = (const float*)d_in[0];
  const float* k_x = (const float*)d_in[1];
  const float* v_x = (const float*)d_in[2];
  const float* E   = (const float*)d_in[3];
  const float* Wq  = (const float*)d_in[4];
  const float* bq  = (const float*)d_in[5];
  const float* Wk  = (const float*)d_in[6];
  const float* bk  = (const float*)d_in[7];
  const float* Wv  = (const float*)d_in[8];
  const float* bv  = (const float*)d_in[9];
  const float* Wo  = (const float*)d_in[10];
  const float* bo  = (const float*)d_in[11];
  float* out = (float*)d_out;

  char* w = (char*)d_ws;
  unsigned short* Wtq  = (unsigned short*)(w + 0);          // 6 MB
  unsigned short* Wtk  = (unsigned short*)(w + 6291456);    // 6 MB
  unsigned short* Wtv  = (unsigned short*)(w + 12582912);   // 2 MB
  unsigned short* Wto  = (unsigned short*)(w + 14680064);   // 2 MB
  unsigned short* Xqk  = (unsigned short*)(w + 16777216);   // 8192x3072 bf16 = 48 MB
  // region reuse after QK GEMM completes (stream-ordered):
  unsigned short* Xv   = (unsigned short*)(w + 16777216);   // 8 MB
  float*          Ytmp = (float*)(w + 25165824);            // 16 MB
  unsigned short* Vtp  = (unsigned short*)(w + 41943040);   // 8 MB
  unsigned short* Obf  = (unsigned short*)(w + 50331648);   // 8 MB
  unsigned short* Qp   = (unsigned short*)(w + 67108864);   // 8 MB
  unsigned short* Kpp  = (unsigned short*)(w + 75497472);   // 8 MB
  float*          gate = (float*)(w + 83886080);            // 16 KB

  k_gate<<<16, 256, 0, stream>>>(E, gate);

  k_pack_wT_split<<<dim3(32, 32), 256, 0, stream>>>(Wq, Wtq);
  k_pack_wT_split<<<dim3(32, 32), 256, 0, stream>>>(Wk, Wtk);
  k_pack_wT_plain<<<dim3(32, 32), 256, 0, stream>>>(Wv, Wtv);
  k_pack_wT_plain<<<dim3(32, 32), 256, 0, stream>>>(Wo, Wto);

  // Q and K inputs packed (bf16x3 split) into one stacked A matrix (8192 x 3072)
  k_pack_split<<<2048, 256, 0, stream>>>(q_x, Xqk);
  k_pack_split<<<2048, 256, 0, stream>>>(k_x, Xqk + (size_t)4096 * 3072);

  // fused Q+K projection, per-head bf16 epilogue (Q scaled by 0.125*log2e)
  k_gemm_qk<<<dim3(64, 8), 256, 0, stream>>>(Xqk, Wtq, Wtk, bq, bk, Qp, Kpp);

  // V projection (plain bf16), gate folded into V rows, stored transposed per head
  k_pack_plain<<<2048, 256, 0, stream>>>(v_x, Xv);
  k_gemm_f32<1024><<<dim3(32, 8), 256, 0, stream>>>(Xv, Wtv, bv, Ytmp);
  k_pack_v<<<dim3(64, 32), 256, 0, stream>>>(Ytmp, gate, Vtp);

  // attention -> bf16 (b,l,1024)
  k_flash<<<dim3(32, 16), 256, 0, stream>>>(Qp, Kpp, Vtp, Obf);

  // output projection
  k_gemm_f32<1024><<<dim3(32, 8), 256, 0, stream>>>(Obf, Wto, bo, out);
}

// Round 6
// 205.018 us; speedup vs baseline: 3.0868x; 1.0328x over previous
//
#include <hip/hip_runtime.h>

typedef __attribute__((ext_vector_type(8))) short bf16x8;
typedef __attribute__((ext_vector_type(8))) unsigned short u16x8;
typedef __attribute__((ext_vector_type(4))) float f32x4;

#define DEVI static __device__ __forceinline__

// async global->LDS, 16B per lane; gp per-lane, lp wave-uniform
typedef const __attribute__((address_space(1))) void cglobal_void;
typedef __attribute__((address_space(3))) void lds_void;
#define GLD16(gp, lp) __builtin_amdgcn_global_load_lds((cglobal_void*)(gp), (lds_void*)(lp), 16, 0, 0)

// Problem constants: B=2, L=2048, D=1024, H=16, Dh=64
constexpr int K3 = 3072;      // tripled K for split GEMMs

DEVI unsigned short f2bf(float x) {
  unsigned int u = __builtin_bit_cast(unsigned int, x);
  u += 0x7fffu + ((u >> 16) & 1u);   // round-to-nearest-even
  return (unsigned short)(u >> 16);
}
DEVI float bf2f(unsigned short v) {
  unsigned int u = ((unsigned int)v) << 16;
  return __builtin_bit_cast(float, u);
}
// hardware packed f32x2 -> bf16x2 (RNE), single VALU op
DEVI unsigned int cvtpk_bf16(float lo, float hi) {
  unsigned int r;
  asm("v_cvt_pk_bf16_f32 %0, %1, %2" : "=v"(r) : "v"(lo), "v"(hi));
  return r;
}

// ---------------- gate: sigmoid((mean|E| - 0.1)*10) per (b,l) key ----------------
__global__ void k_gate(const float* __restrict__ E, float* __restrict__ gate) {
  int i = blockIdx.x * 256 + threadIdx.x;           // 0..4095
  const float4* e = reinterpret_cast<const float4*>(E);
  float4 a = e[i * 2], b = e[i * 2 + 1];
  float s = fabsf(a.x) + fabsf(a.y) + fabsf(a.z) + fabsf(a.w)
          + fabsf(b.x) + fabsf(b.y) + fabsf(b.z) + fabsf(b.w);
  float en = s * 0.125f;
  gate[i] = 1.0f / (1.0f + __expf(-10.0f * (en - 0.1f)));
}

// ---------------- pack X (4096 x 1024 f32) -> [hi|hi|lo] (4096 x 3072 bf16) ----------------
__global__ void k_pack_split(const float* __restrict__ X, unsigned short* __restrict__ Xp) {
  int t = blockIdx.x * 256 + threadIdx.x;
  int idx = t << 3;
  int m = idx >> 10, k = idx & 1023;
  const float4* src = reinterpret_cast<const float4*>(X + idx);
  float4 a = src[0], b = src[1];
  float xs[8] = {a.x, a.y, a.z, a.w, b.x, b.y, b.z, b.w};
  u16x8 hi, lo;
#pragma unroll
  for (int j = 0; j < 8; ++j) {
    unsigned short h = f2bf(xs[j]);
    hi[j] = h;
    lo[j] = f2bf(xs[j] - bf2f(h));
  }
  unsigned short* base = Xp + (size_t)m * K3 + k;
  *reinterpret_cast<u16x8*>(base) = hi;
  *reinterpret_cast<u16x8*>(base + 1024) = hi;
  *reinterpret_cast<u16x8*>(base + 2048) = lo;
}

// ---------------- pack X (N x 1024 f32) -> plain bf16 (N x 1024) ----------------
__global__ void k_pack_plain(const float* __restrict__ X, unsigned short* __restrict__ Xp) {
  int t = blockIdx.x * 256 + threadIdx.x;
  int idx = t << 3;
  const float4* src = reinterpret_cast<const float4*>(X + idx);
  float4 a = src[0], b = src[1];
  float xs[8] = {a.x, a.y, a.z, a.w, b.x, b.y, b.z, b.w};
  u16x8 hi;
#pragma unroll
  for (int j = 0; j < 8; ++j) hi[j] = f2bf(xs[j]);
  *reinterpret_cast<u16x8*>(Xp + idx) = hi;
}

// ---------------- pack W (1024x1024) -> transposed split (1024 x 3072) [hi|lo|hi] ----------------
__global__ void k_pack_wT_split(const float* __restrict__ W, unsigned short* __restrict__ Wt) {
  __shared__ float tile[32][33];
  int tx = threadIdx.x & 31, ty = threadIdx.x >> 5;    // ty in [0,8)
  int kb = blockIdx.x * 32, nb = blockIdx.y * 32;
#pragma unroll
  for (int i = 0; i < 4; ++i)
    tile[ty + 8 * i][tx] = W[(size_t)(kb + ty + 8 * i) * 1024 + nb + tx];
  __syncthreads();
#pragma unroll
  for (int i = 0; i < 4; ++i) {
    int n = nb + ty + 8 * i;
    int k = kb + tx;
    float x = tile[tx][ty + 8 * i];
    unsigned short h = f2bf(x);
    unsigned short l = f2bf(x - bf2f(h));
    unsigned short* base = Wt + (size_t)n * K3;
    base[k] = h;
    base[1024 + k] = l;
    base[2048 + k] = h;
  }
}

// ---------------- pack W (1024x1024) -> transposed plain bf16 (1024 x 1024) ----------------
__global__ void k_pack_wT_plain(const float* __restrict__ W, unsigned short* __restrict__ Wt) {
  __shared__ float tile[32][33];
  int tx = threadIdx.x & 31, ty = threadIdx.x >> 5;
  int kb = blockIdx.x * 32, nb = blockIdx.y * 32;
#pragma unroll
  for (int i = 0; i < 4; ++i)
    tile[ty + 8 * i][tx] = W[(size_t)(kb + ty + 8 * i) * 1024 + nb + tx];
  __syncthreads();
#pragma unroll
  for (int i = 0; i < 4; ++i) {
    int n = nb + ty + 8 * i;
    int k = kb + tx;
    Wt[(size_t)n * 1024 + k] = f2bf(tile[tx][ty + 8 * i]);
  }
}

// ---------------- pack V: Y (N x 1024 f32) -> gated transposed per-head (bh, d, L) bf16 ----------------
__global__ void k_pack_v(const float* __restrict__ Y, const float* __restrict__ gate,
                         unsigned short* __restrict__ Vt) {
  __shared__ float tile[32][65];
  int bh = blockIdx.y;
  int b = bh >> 4, h = bh & 15;
  int l0 = blockIdx.x * 32;
  int tx = threadIdx.x & 63, ty = threadIdx.x >> 6;   // read: tx = d, ty+4i = l-local
#pragma unroll
  for (int i = 0; i < 8; ++i) {
    int ll = ty + 4 * i;
    float g = gate[b * 2048 + l0 + ll];
    tile[ll][tx] = Y[(size_t)(b * 2048 + l0 + ll) * 1024 + h * 64 + tx] * g;
  }
  __syncthreads();
  int lx = threadIdx.x & 31, dy = threadIdx.x >> 5;   // write: lx = l-local, d = dy + 8i
#pragma unroll
  for (int i = 0; i < 8; ++i) {
    int d = dy + 8 * i;
    Vt[((size_t)bh * 64 + d) * 2048 + l0 + lx] = f2bf(tile[lx][d]);
  }
}

// ---------------- GEMM main loop: 128x128 tile, BK=64, dbuf LDS + global_load_lds prefetch ----------------
// LDS: linear dest rows of 128B; source chunk pre-swizzled c^(r&7); ds_read at q^(r&7).
template <int KD>
DEVI void gemm_tile(const unsigned short* __restrict__ A,
                    const unsigned short* __restrict__ Bt,
                    unsigned short* sA0, unsigned short* sB0,
                    int m0, int n0, int tid, f32x4 acc[4][4]) {
  const int lane = tid & 63;
  const int l15 = lane & 15, l4 = lane >> 4;
  const int wave = tid >> 6;
  const int wr = wave >> 1, wc = wave & 1;
  const int wofs = (tid & 192) * 16;       // wave*1024 bytes: wave-uniform LDS base offset

  auto stage = [&](int buf, int k0) {
    unsigned short* dA = sA0 + buf * 8192;
    unsigned short* dB = sB0 + buf * 8192;
#pragma unroll
    for (int i = 0; i < 4; ++i) {
      int id = i * 256 + tid;
      int r = id >> 3, c = id & 7;
      GLD16(A + (size_t)(m0 + r) * KD + k0 + ((c ^ (r & 7)) << 3), (char*)dA + i * 4096 + wofs);
    }
#pragma unroll
    for (int i = 0; i < 4; ++i) {
      int id = i * 256 + tid;
      int r = id >> 3, c = id & 7;
      GLD16(Bt + (size_t)(n0 + r) * KD + k0 + ((c ^ (r & 7)) << 3), (char*)dB + i * 4096 + wofs);
    }
  };

  stage(0, 0);
  int cur = 0;
  for (int k0 = 0; k0 < KD; k0 += 64) {
    __syncthreads();   // drains vmcnt for tile k0; also protects buf cur^1 writes
    if (k0 + 64 < KD) stage(cur ^ 1, k0 + 64);
    const unsigned short* cA = sA0 + cur * 8192;
    const unsigned short* cB = sB0 + cur * 8192;
#pragma unroll
    for (int kc = 0; kc < 2; ++kc) {
      bf16x8 af[4], bfr[4];
#pragma unroll
      for (int f = 0; f < 4; ++f) {
        int r = wr * 64 + f * 16 + l15;
        af[f] = *reinterpret_cast<const bf16x8*>(
            reinterpret_cast<const char*>(cA) + r * 128 + (((kc * 4 + l4) ^ (r & 7)) * 16));
      }
#pragma unroll
      for (int f = 0; f < 4; ++f) {
        int r = wc * 64 + f * 16 + l15;
        bfr[f] = *reinterpret_cast<const bf16x8*>(
            reinterpret_cast<const char*>(cB) + r * 128 + (((kc * 4 + l4) ^ (r & 7)) * 16));
      }
#pragma unroll
      for (int fm = 0; fm < 4; ++fm)
#pragma unroll
        for (int fn = 0; fn < 4; ++fn)
          acc[fm][fn] = __builtin_amdgcn_mfma_f32_16x16x32_bf16(af[fm], bfr[fn], acc[fm][fn], 0, 0, 0);
    }
    cur ^= 1;
  }
}

// ---------------- fused Q+K projection GEMM (M=8192 stacked), bf16 per-head epilogue ----------------
// Q epilogue scale folds 1/sqrt(Dh) AND log2(e) so flash softmax runs in exp2 domain.
__global__ __launch_bounds__(256) void k_gemm_qk(const unsigned short* __restrict__ A,
                                                 const unsigned short* __restrict__ WtQ,
                                                 const unsigned short* __restrict__ WtK,
                                                 const float* __restrict__ bq,
                                                 const float* __restrict__ bk,
                                                 unsigned short* __restrict__ Qp,
                                                 unsigned short* __restrict__ Kp) {
  __shared__ unsigned short sA[2][128 * 64];   // 32KB
  __shared__ unsigned short sB[2][128 * 64];   // 32KB
  const int tid = threadIdx.x;
  const int lane = tid & 63, wave = tid >> 6;
  const int l15 = lane & 15, l4 = lane >> 4;
  const int wr = wave >> 1, wc = wave & 1;
  const int m0 = blockIdx.x * 128, n0 = blockIdx.y * 128;
  const bool isK = (m0 >= 4096);
  const unsigned short* Bt = isK ? WtK : WtQ;
  const float* bias = isK ? bk : bq;
  unsigned short* Out = isK ? Kp : Qp;
  const float scale = isK ? 1.0f : 0.18033688011112042f;  // 0.125 * log2(e)

  const f32x4 zero4 = {0.f, 0.f, 0.f, 0.f};
  f32x4 acc[4][4];
#pragma unroll
  for (int i = 0; i < 4; ++i)
#pragma unroll
    for (int j = 0; j < 4; ++j) acc[i][j] = zero4;

  gemm_tile<3072>(A, Bt, &sA[0][0], &sB[0][0], m0, n0, tid, acc);

#pragma unroll
  for (int fm = 0; fm < 4; ++fm)
#pragma unroll
    for (int fn = 0; fn < 4; ++fn) {
      int col = n0 + wc * 64 + fn * 16 + l15;
      int h = col >> 6, d = col & 63;
      float bv = bias[col];
#pragma unroll
      for (int j = 0; j < 4; ++j) {
        int rowg = m0 + wr * 64 + fm * 16 + l4 * 4 + j;
        int rowm = rowg & 4095;
        int b = rowm >> 11, l = rowm & 2047;
        float v = (acc[fm][fn][j] + bv) * scale;
        Out[(((size_t)(b * 16 + h) * 2048 + l) << 6) + d] = f2bf(v);
      }
    }
}

// ---------------- plain GEMM, f32 + bias epilogue (V proj, O proj) ----------------
template <int KD>
__global__ __launch_bounds__(256) void k_gemm_f32(const unsigned short* __restrict__ A,
                                                  const unsigned short* __restrict__ Bt,
                                                  const float* __restrict__ bias,
                                                  float* __restrict__ C) {
  __shared__ unsigned short sA[2][128 * 64];
  __shared__ unsigned short sB[2][128 * 64];
  const int tid = threadIdx.x;
  const int lane = tid & 63, wave = tid >> 6;
  const int l15 = lane & 15, l4 = lane >> 4;
  const int wr = wave >> 1, wc = wave & 1;
  const int m0 = blockIdx.x * 128, n0 = blockIdx.y * 128;

  const f32x4 zero4 = {0.f, 0.f, 0.f, 0.f};
  f32x4 acc[4][4];
#pragma unroll
  for (int i = 0; i < 4; ++i)
#pragma unroll
    for (int j = 0; j < 4; ++j) acc[i][j] = zero4;

  gemm_tile<KD>(A, Bt, &sA[0][0], &sB[0][0], m0, n0, tid, acc);

#pragma unroll
  for (int fm = 0; fm < 4; ++fm)
#pragma unroll
    for (int fn = 0; fn < 4; ++fn) {
      int col = n0 + wc * 64 + fn * 16 + l15;
      float bv = bias[col];
#pragma unroll
      for (int j = 0; j < 4; ++j) {
        int row = m0 + wr * 64 + fm * 16 + l4 * 4 + j;
        C[(size_t)row * 1024 + col] = acc[fm][fn][j] + bv;
      }
    }
}

// ---------------- flash attention, swapped-QK in-register softmax (exp2 domain) ----------------
// Per (b,h), 64 q-rows/block (4 waves x 16q), KV tiles of 64, dbuf K/V staging.
// S^T = mfma(K,Q): lane holds S[k=fk*16+l4*4+j][q=l15] -> row-reduce is in-lane.
// grid 1024 blocks -> 4 blocks/CU (LDS 40KB), 16 waves/CU.
__global__ __launch_bounds__(256) void k_flash(const unsigned short* __restrict__ Qp,
                                               const unsigned short* __restrict__ Kp,
                                               const unsigned short* __restrict__ Vt,
                                               unsigned short* __restrict__ O) {
  __shared__ unsigned short sK[2][64 * 64];   // 16KB
  __shared__ unsigned short sV[2][64 * 64];   // 16KB (V^T: rows=d, cols=keys)
  __shared__ unsigned short sP[4][16 * 64];   // 8KB, per-wave P tile (16 q-rows x 128B)
  const int tid = threadIdx.x;
  const int lane = tid & 63, wave = tid >> 6;
  const int l15 = lane & 15, l4 = lane >> 4;
  const int bh = blockIdx.x;
  const int q0 = blockIdx.y * 64;
  const int b = bh >> 4, h = bh & 15;
  const size_t hBase = (size_t)bh * 2048 * 64;
  const int wofs = (tid & 192) * 16;          // wave-uniform LDS offset

  // Q fragment (B-operand): col=q (l15), k-elems kc*32 + l4*8..+7. Q pre-scaled by 0.125*log2e.
  const int qrow = q0 + wave * 16 + l15;
  bf16x8 qf[2];
#pragma unroll
  for (int kc = 0; kc < 2; ++kc)
    qf[kc] = *reinterpret_cast<const bf16x8*>(Qp + hBase + (size_t)qrow * 64 + kc * 32 + l4 * 8);

  const f32x4 zero4 = {0.f, 0.f, 0.f, 0.f};
  f32x4 accO[4];
  float m = -1.0e30f, lp = 0.f;   // running max (log2 units), per-lane PARTIAL denom
#pragma unroll
  for (int fd = 0; fd < 4; ++fd) accO[fd] = zero4;

  auto stage = [&](int buf, int kv0) {
#pragma unroll
    for (int i = 0; i < 2; ++i) {
      int id = i * 256 + tid;
      int r = id >> 3, c = id & 7;
      int sc = (c ^ (r & 7)) << 3;
      GLD16(Kp + hBase + (size_t)(kv0 + r) * 64 + sc, (char*)sK[buf] + i * 4096 + wofs);
      GLD16(Vt + hBase + (size_t)r * 2048 + kv0 + sc, (char*)sV[buf] + i * 4096 + wofs);
    }
  };

  char* pb = reinterpret_cast<char*>(&sP[wave][0]);
  const int qm = (l15 & 7) << 4;
  char* rowb = pb + l15 * 128;
  stage(0, 0);
  int cur = 0;

  for (int kv0 = 0; kv0 < 2048; kv0 += 64) {
    __syncthreads();   // tile kv0 staged; all waves done reading buf cur^1
    if (kv0 + 64 < 2048) stage(cur ^ 1, kv0 + 64);

    // S^T = K Q^T: s[fk], C row = k (l4*4+j), col = q (l15)
    f32x4 s[4];
#pragma unroll
    for (int fk = 0; fk < 4; ++fk) s[fk] = zero4;
#pragma unroll
    for (int kc = 0; kc < 2; ++kc) {
      bf16x8 kf[4];
#pragma unroll
      for (int fk = 0; fk < 4; ++fk) {
        int r = fk * 16 + l15;
        kf[fk] = *reinterpret_cast<const bf16x8*>(
            reinterpret_cast<const char*>(sK[cur]) + r * 128 + (((kc * 4 + l4) ^ (r & 7)) * 16));
      }
#pragma unroll
      for (int fk = 0; fk < 4; ++fk)
        s[fk] = __builtin_amdgcn_mfma_f32_16x16x32_bf16(kf[fk], qf[kc], s[fk], 0, 0, 0);
    }

    // per-lane tile max (16 values for q-column l15)
    float t0 = fmaxf(fmaxf(s[0][0], s[0][1]), fmaxf(s[0][2], s[0][3]));
    float t1 = fmaxf(fmaxf(s[1][0], s[1][1]), fmaxf(s[1][2], s[1][3]));
    float t2 = fmaxf(fmaxf(s[2][0], s[2][1]), fmaxf(s[2][2], s[2][3]));
    float t3 = fmaxf(fmaxf(s[3][0], s[3][1]), fmaxf(s[3][2], s[3][3]));
    float pmax = fmaxf(fmaxf(t0, t1), fmaxf(t2, t3));
    // defer-max: skip reduce+rescale while tile max stays within 8 (log2) of running max
    if (!__all(pmax <= m + 8.f)) {
      float t = pmax;
      t = fmaxf(t, __shfl_xor(t, 16));
      t = fmaxf(t, __shfl_xor(t, 32));
      float mn = fmaxf(m, t);
      float a = exp2f(m - mn);
      lp *= a;
      m = mn;
#pragma unroll
      for (int j = 0; j < 4; ++j) {
        float aj = __shfl(a, (lane & 48) | (l4 * 4 + j), 64);
#pragma unroll
        for (int fd = 0; fd < 4; ++fd) accO[fd][j] *= aj;
      }
    }
    // p = 2^(s-m); per-lane partial denom; pack to LDS via v_cvt_pk_bf16_f32
    // swizzle: pure XOR of bits 4-6 with (q&7) -> bijective, write/read consistent
    float sum = 0.f;
#pragma unroll
    for (int fk = 0; fk < 4; ++fk) {
      float p0 = exp2f(s[fk][0] - m);
      float p1 = exp2f(s[fk][1] - m);
      float p2 = exp2f(s[fk][2] - m);
      float p3 = exp2f(s[fk][3] - m);
      sum += (p0 + p1) + (p2 + p3);
      uint2 wv;
      wv.x = cvtpk_bf16(p0, p1);
      wv.y = cvtpk_bf16(p2, p3);
      *reinterpret_cast<uint2*>(rowb + ((fk * 32 + l4 * 8) ^ qm)) = wv;
    }
    lp += sum;

    // O += P * V  (A = P rows q, B = V^T rows d)
#pragma unroll
    for (int kc = 0; kc < 2; ++kc) {
      bf16x8 pf = *reinterpret_cast<const bf16x8*>(rowb + ((kc * 64 + l4 * 16) ^ qm));
      bf16x8 vf[4];
#pragma unroll
      for (int fd = 0; fd < 4; ++fd) {
        int r = fd * 16 + l15;
        vf[fd] = *reinterpret_cast<const bf16x8*>(
            reinterpret_cast<const char*>(sV[cur]) + r * 128 + (((kc * 4 + l4) ^ (r & 7)) * 16));
      }
#pragma unroll
      for (int fd = 0; fd < 4; ++fd)
        accO[fd] = __builtin_amdgcn_mfma_f32_16x16x32_bf16(pf, vf[fd], accO[fd], 0, 0, 0);
    }
    cur ^= 1;
  }

  // epilogue: reduce partial denoms across l4, broadcast into C-row space, divide, store bf16
  lp += __shfl_xor(lp, 16);
  lp += __shfl_xor(lp, 32);
#pragma unroll
  for (int j = 0; j < 4; ++j) {
    float li = 1.0f / __shfl(lp, (lane & 48) | (l4 * 4 + j), 64);
    int qw = q0 + wave * 16 + l4 * 4 + j;
#pragma unroll
    for (int fd = 0; fd < 4; ++fd) {
      int col = h * 64 + fd * 16 + l15;
      O[(size_t)(b * 2048 + qw) * 1024 + col] = f2bf(accO[fd][j] * li);
    }
  }
}

extern "C" void kernel_launch(void* const* d_in, const int* in_sizes, int n_in,
                              void* d_out, int out_size, void* d_ws, size_t ws_size,
                              hipStream_t stream) {
  const float* q_x = (const float*)d_in[0];
  const float* k_x = (const float*)d_in[1];
  const float* v_x = (const float*)d_in[2];
  const float* E   = (const float*)d_in[3];
  const float* Wq  = (const float*)d_in[4];
  const float* bq  = (const float*)d_in[5];
  const float* Wk  = (const float*)d_in[6];
  const float* bk  = (const float*)d_in[7];
  const float* Wv  = (const float*)d_in[8];
  const float* bv  = (const float*)d_in[9];
  const float* Wo  = (const float*)d_in[10];
  const float* bo  = (const float*)d_in[11];
  float* out = (float*)d_out;

  char* w = (char*)d_ws;
  unsigned short* Wtq  = (unsigned short*)(w + 0);          // 6 MB
  unsigned short* Wtk  = (unsigned short*)(w + 6291456);    // 6 MB
  unsigned short* Wtv  = (unsigned short*)(w + 12582912);   // 2 MB
  unsigned short* Wto  = (unsigned short*)(w + 14680064);   // 2 MB
  unsigned short* Xqk  = (unsigned short*)(w + 16777216);   // 8192x3072 bf16 = 48 MB
  // region reuse after QK GEMM completes (stream-ordered):
  unsigned short* Xv   = (unsigned short*)(w + 16777216);   // 8 MB
  float*          Ytmp = (float*)(w + 25165824);            // 16 MB
  unsigned short* Vtp  = (unsigned short*)(w + 41943040);   // 8 MB
  unsigned short* Obf  = (unsigned short*)(w + 50331648);   // 8 MB
  unsigned short* Qp   = (unsigned short*)(w + 67108864);   // 8 MB
  unsigned short* Kpp  = (unsigned short*)(w + 75497472);   // 8 MB
  float*          gate = (float*)(w + 83886080);            // 16 KB

  k_gate<<<16, 256, 0, stream>>>(E, gate);

  k_pack_wT_split<<<dim3(32, 32), 256, 0, stream>>>(Wq, Wtq);
  k_pack_wT_split<<<dim3(32, 32), 256, 0, stream>>>(Wk, Wtk);
  k_pack_wT_plain<<<dim3(32, 32), 256, 0, stream>>>(Wv, Wtv);
  k_pack_wT_plain<<<dim3(32, 32), 256, 0, stream>>>(Wo, Wto);

  // Q and K inputs packed (bf16x3 split) into one stacked A matrix (8192 x 3072)
  k_pack_split<<<2048, 256, 0, stream>>>(q_x, Xqk);
  k_pack_split<<<2048, 256, 0, stream>>>(k_x, Xqk + (size_t)4096 * 3072);

  // fused Q+K projection, per-head bf16 epilogue (Q scaled by 0.125*log2e)
  k_gemm_qk<<<dim3(64, 8), 256, 0, stream>>>(Xqk, Wtq, Wtk, bq, bk, Qp, Kpp);

  // V projection (plain bf16), gate folded into V rows, stored transposed per head
  k_pack_plain<<<2048, 256, 0, stream>>>(v_x, Xv);
  k_gemm_f32<1024><<<dim3(32, 8), 256, 0, stream>>>(Xv, Wtv, bv, Ytmp);
  k_pack_v<<<dim3(64, 32), 256, 0, stream>>>(Ytmp, gate, Vtp);

  // attention -> bf16 (b,l,1024)
  k_flash<<<dim3(32, 32), 256, 0, stream>>>(Qp, Kpp, Vtp, Obf);

  // output projection
  k_gemm_f32<1024><<<dim3(32, 8), 256, 0, stream>>>(Obf, Wto, bo, out);
}